// Round 8
// baseline (48.962 us; speedup 1.0000x reference)
//
#include <hip/hip_runtime.h>

#define IN_H 200
#define IN_W 200
#define NCH  256
#define NROI 512
#define OUT_HW 49
#define PLANE (IN_H * IN_W)

// ---------------- kernel 1: NCHW f32 -> NHWC bf16 ----------------
__global__ __launch_bounds__(256) void transpose_bf16_kernel(
    const float* __restrict__ in, ushort* __restrict__ nhwc) {
  __shared__ ushort t[64][260];
  const int blk = blockIdx.x;
  const int hwt = blk % 625;
  const int b   = blk / 625;
  const int w = threadIdx.x >> 6, l = threadIdx.x & 63;
  const int hw0 = hwt * 64;

  const float* src = in + (size_t)b * NCH * PLANE + hw0;
#pragma unroll 4
  for (int i = 0; i < 64; ++i) {
    const int c = w * 64 + i;
    const float v = src[(size_t)c * PLANE + l];
    const unsigned u = __float_as_uint(v);
    const unsigned r = (u + 0x7fffu + ((u >> 16) & 1u)) >> 16;  // RN-even
    t[l][c] = (ushort)r;
  }
  __syncthreads();

  ushort* dst = nhwc + ((size_t)b * PLANE + hw0) * NCH;
#pragma unroll
  for (int m = threadIdx.x; m < 64 * 64; m += 256) {
    const int h = m >> 6;
    const int q = m & 63;
    *(ushort4*)(dst + (size_t)h * NCH + q * 4) = *(const ushort4*)&t[h][q * 4];
  }
}

__device__ inline void acc8(float* acc, uint4 q, float w) {
  acc[0] += w * __uint_as_float(q.x << 16);
  acc[1] += w * __uint_as_float(q.x & 0xffff0000u);
  acc[2] += w * __uint_as_float(q.y << 16);
  acc[3] += w * __uint_as_float(q.y & 0xffff0000u);
  acc[4] += w * __uint_as_float(q.z << 16);
  acc[5] += w * __uint_as_float(q.z & 0xffff0000u);
  acc[6] += w * __uint_as_float(q.w << 16);
  acc[7] += w * __uint_as_float(q.w & 0xffff0000u);
}

// axis structure: 2 samples -> up to 4 (index,weight) pairs, merged when equal.
// outputs named scalars; e2/e3 enable the 3rd/4th entry.
__device__ inline void axis_struct(float s0, float s1, int limit,
                                   int& i0, int& i1, int& i2, int& i3,
                                   float& w0, float& w1, float& w2, float& w3,
                                   bool& e2, bool& e3) {
  const float lim = (float)limit;
  const float c0 = fminf(fmaxf(s0, 0.0f), lim);
  const float f0 = floorf(c0);
  const int   a0 = (int)f0;
  const int   b0 = min(a0 + 1, limit);
  const float l0 = c0 - f0, h0 = 1.0f - l0;

  const float c1 = fminf(fmaxf(s1, 0.0f), lim);
  const float f1 = floorf(c1);
  const int   a1 = (int)f1;
  const int   b1 = min(a1 + 1, limit);
  const float l1 = c1 - f1, h1 = 1.0f - l1;

  i0 = a0; i1 = b0; w0 = h0; w1 = l0;
  if (a1 == a0) {          // 2 unique (b1==b0 too)
    w0 += h1; w1 += l1; e2 = false; e3 = false; i2 = i3 = a0;
  } else if (a1 == b0) {   // 3 unique: a0, b0, b1
    w1 += h1; i2 = b1; w2 = l1; e2 = true; e3 = false; i3 = a0;
  } else {                 // 4 unique
    i2 = a1; w2 = h1; i3 = b1; w3 = l1; e2 = true; e3 = true;
  }
}

// ---------------- kernel 2: ROIAlign from bf16 NHWC, deduped corners ----------------
// block = half a roi (128 ch); 256 thr; thread: 8 ch (uint4), 16 px-groups
__global__ __launch_bounds__(256) void roi_nhwc_bf16_kernel(
    const ushort* __restrict__ nhwc,
    const float* __restrict__ rois,
    float* __restrict__ out) {
  __shared__ float sout[128 * OUT_HW];  // 25088 B

  const int blk  = blockIdx.x;
  const int k    = blk >> 1;
  const int half = blk & 1;
  const int t    = threadIdx.x;
  const int pg   = t >> 4;             // 0..15
  const int cl   = (t & 15) * 8;       // local channel 0..120
  const int c0   = half * 128 + cl;

  const float* r = rois + k * 5;
  const int   b   = (int)r[0];
  const float x1s = r[1] * 0.25f;
  const float y1s = r[2] * 0.25f;
  const float x2s = r[3] * 0.25f;
  const float y2s = r[4] * 0.25f;
  const float roi_w = fmaxf(x2s - x1s, 1.0f);
  const float roi_h = fmaxf(y2s - y1s, 1.0f);
  const float bw = roi_w / 7.0f;
  const float bh = roi_h / 7.0f;

  // whole-roi validity (coords monotone: min at p=0,i=0; max at p=6,i=1)
  const bool valid = (y1s + 0.25f * bh >= -1.0f) && (y1s + 6.75f * bh <= (float)IN_H) &&
                     (x1s + 0.25f * bw >= -1.0f) && (x1s + 6.75f * bw <= (float)IN_W);
  const float scale = valid ? 0.25f : 0.0f;

  const ushort* base = nhwc + (size_t)b * PLANE * NCH + c0;

  for (int p = pg; p < OUT_HW; p += 16) {
    const int ph = p / 7;
    const int pw = p - ph * 7;
    const float ybase = y1s + bh * (float)ph;
    const float xbase = x1s + bw * (float)pw;

    // y axis: samples at ybase + 0.25bh, ybase + 0.75bh
    int ry0, ry1, ry2, ry3; float wy0, wy1, wy2, wy3; bool ey2, ey3;
    axis_struct(ybase + 0.25f * bh, ybase + 0.75f * bh, IN_H - 1,
                ry0, ry1, ry2, ry3, wy0, wy1, wy2, wy3, ey2, ey3);
    // x axis
    int cx0, cx1, cx2, cx3; float wx0, wx1, wx2, wx3; bool ex2, ex3;
    axis_struct(xbase + 0.25f * bw, xbase + 0.75f * bw, IN_W - 1,
                cx0, cx1, cx2, cx3, wx0, wx1, wx2, wx3, ex2, ex3);

    const size_t co0 = (size_t)cx0 * NCH;
    const size_t co1 = (size_t)cx1 * NCH;
    const size_t co2 = (size_t)cx2 * NCH;
    const size_t co3 = (size_t)cx3 * NCH;

    float acc[8] = {0.f, 0.f, 0.f, 0.f, 0.f, 0.f, 0.f, 0.f};

#define ROW(RY, WY)                                                        \
    {                                                                      \
      const ushort* rp = base + (size_t)(RY) * (IN_W * NCH);               \
      acc8(acc, *(const uint4*)(rp + co0), (WY) * wx0);                    \
      acc8(acc, *(const uint4*)(rp + co1), (WY) * wx1);                    \
      if (ex2) acc8(acc, *(const uint4*)(rp + co2), (WY) * wx2);           \
      if (ex3) acc8(acc, *(const uint4*)(rp + co3), (WY) * wx3);           \
    }
    ROW(ry0, wy0)
    ROW(ry1, wy1)
    if (ey2) ROW(ry2, wy2)
    if (ey3) ROW(ry3, wy3)
#undef ROW

#pragma unroll
    for (int j = 0; j < 8; ++j) sout[(cl + j) * OUT_HW + p] = acc[j] * scale;
  }
  __syncthreads();

  // contiguous coalesced write of this half-roi's (128,7,7) tile
  float4* o4 = (float4*)(out + ((size_t)k * NCH + half * 128) * OUT_HW);
  const float4* s4 = (const float4*)sout;
  for (int m = t; m < (128 * OUT_HW) / 4; m += 256) o4[m] = s4[m];
}

// ---------------- fallback (ws too small): direct gather, f32 NCHW ----------------
__global__ __launch_bounds__(256) void roi_align_fallback(
    const float* __restrict__ input,
    const float* __restrict__ rois,
    float* __restrict__ out) {
  const int blk  = blockIdx.x;
  const int k    = blk >> 6;
  const int cg   = blk & 63;
  const int wave = threadIdx.x >> 6;
  const int lane = threadIdx.x & 63;
  const int c    = (cg << 2) + wave;

  const float* r = rois + k * 5;
  const int   b   = (int)r[0];
  const float x1s = r[1] * 0.25f;
  const float y1s = r[2] * 0.25f;
  const float roi_w = fmaxf(r[3] * 0.25f - x1s, 1.0f);
  const float roi_h = fmaxf(r[4] * 0.25f - y1s, 1.0f);
  const float bw = roi_w / 7.0f;
  const float bh = roi_h / 7.0f;
  const bool valid = (y1s + 0.25f * bh >= -1.0f) && (y1s + 6.75f * bh <= (float)IN_H) &&
                     (x1s + 0.25f * bw >= -1.0f) && (x1s + 6.75f * bw <= (float)IN_W);
  if (lane >= OUT_HW) return;
  const int ph = lane / 7;
  const int pw = lane - ph * 7;
  const float* plane = input + ((size_t)(b * NCH + c)) * PLANE;
  const float ybase = y1s + bh * (float)ph;
  const float xbase = x1s + bw * (float)pw;
  float acc = 0.0f;
#pragma unroll
  for (int iy = 0; iy < 2; ++iy) {
    const float y  = ybase + (bh * 0.5f) * ((float)iy + 0.5f);
    const float yc = fminf(fmaxf(y, 0.0f), (float)(IN_H - 1));
    const float ylf = floorf(yc);
    const int yl = (int)ylf;
    const int yh = min(yl + 1, IN_H - 1);
    const float ly = yc - ylf, hy = 1.0f - ly;
#pragma unroll
    for (int ix = 0; ix < 2; ++ix) {
      const float x  = xbase + (bw * 0.5f) * ((float)ix + 0.5f);
      const float xc = fminf(fmaxf(x, 0.0f), (float)(IN_W - 1));
      const float xlf = floorf(xc);
      const int xl = (int)xlf;
      const int xh = min(xl + 1, IN_W - 1);
      const float lx = xc - xlf, hx = 1.0f - lx;
      const float* row_l = plane + yl * IN_W;
      const float* row_h = plane + yh * IN_W;
      acc += hy * hx * row_l[xl] + hy * lx * row_l[xh] +
             ly * hx * row_h[xl] + ly * lx * row_h[xh];
    }
  }
  out[((size_t)k * NCH + c) * OUT_HW + lane] = valid ? acc * 0.25f : 0.0f;
}

extern "C" void kernel_launch(void* const* d_in, const int* in_sizes, int n_in,
                              void* d_out, int out_size, void* d_ws, size_t ws_size,
                              hipStream_t stream) {
  const float* input = (const float*)d_in[0];
  const float* rois  = (const float*)d_in[1];
  float* out = (float*)d_out;

  const size_t need = (size_t)2 * PLANE * NCH * sizeof(ushort);  // 40.96 MB
  if (ws_size >= need) {
    ushort* nhwc = (ushort*)d_ws;
    transpose_bf16_kernel<<<2 * 625, 256, 0, stream>>>(input, nhwc);
    roi_nhwc_bf16_kernel<<<NROI * 2, 256, 0, stream>>>(nhwc, rois, out);
  } else {
    roi_align_fallback<<<NROI * (NCH / 4), 256, 0, stream>>>(input, rois, out);
  }
}